// Round 15
// baseline (293.427 us; speedup 1.0000x reference)
//
#include <hip/hip_runtime.h>
#include <stdint.h>

typedef __bf16 bf16_t;
typedef __bf16 bf16x8 __attribute__((ext_vector_type(8)));
typedef __bf16 bf16x4 __attribute__((ext_vector_type(4)));
typedef float  f32x4  __attribute__((ext_vector_type(4)));
typedef float  f32x16 __attribute__((ext_vector_type(16)));
typedef unsigned int u32;

#define L2E 1.44269504088896340736f
#define LAMBDA_INIT 0.7836057665316245f
#define ONE_MINUS_LAMBDA_INIT 0.2163942334683755f

// ---------------------------------------------------------------- helpers
__device__ __forceinline__ void gload_lds16(const void* g, void* l) {
  __builtin_amdgcn_global_load_lds(
      (const __attribute__((address_space(1))) char*)(uintptr_t)g,
      (__attribute__((address_space(3))) char*)(uintptr_t)l, 16, 0, 0);
}

__device__ __forceinline__ f32x4 mfma_bf16(bf16x8 a, bf16x8 b, f32x4 c) {
  return __builtin_amdgcn_mfma_f32_16x16x32_bf16(a, b, c, 0, 0, 0);
}
__device__ __forceinline__ f32x16 mfma32(bf16x8 a, bf16x8 b, f32x16 c) {
  return __builtin_amdgcn_mfma_f32_32x32x16_bf16(a, b, c, 0, 0, 0);
}

__device__ __forceinline__ u32 pkbf(float a, float b) {
  union { bf16_t h[2]; u32 u; } x;
  x.h[0] = (bf16_t)a; x.h[1] = (bf16_t)b;
  return x.u;
}
__device__ __forceinline__ void pl32swap(u32& a, u32& b) {
  asm volatile("v_permlane32_swap_b32 %0, %1" : "+v"(a), "+v"(b));
}

// ---------------------------------------------------------------- conversions
__global__ __launch_bounds__(256) void cvt_bf16(const float* __restrict__ in,
                                                bf16_t* __restrict__ out) {
  const size_t idx = ((size_t)blockIdx.x * 256 + threadIdx.x) * 8;
  float4 a = *(const float4*)(in + idx);
  float4 c = *(const float4*)(in + idx + 4);
  bf16x8 v;
  v[0] = (bf16_t)a.x; v[1] = (bf16_t)a.y; v[2] = (bf16_t)a.z; v[3] = (bf16_t)a.w;
  v[4] = (bf16_t)c.x; v[5] = (bf16_t)c.y; v[6] = (bf16_t)c.z; v[7] = (bf16_t)c.w;
  *(bf16x8*)(out + idx) = v;
}

struct WArgs {
  const float* W[4];
  bf16_t* WT[4];
  float sc[4];
};

// W [2048,2048] f32 -> WT [2048,2048] bf16, WT[n][k] = W[k][n]*scale; 4 mats
__global__ __launch_bounds__(256) void cvt_wT_all(WArgs a) {
  __shared__ float t[64][65];
  const int i = blockIdx.z;
  const float* W = a.W[i];
  bf16_t* WT = a.WT[i];
  const float scale = a.sc[i];
  const int k0 = blockIdx.x * 64, n0 = blockIdx.y * 64;
  const int r = threadIdx.x >> 2, cg = threadIdx.x & 3;
#pragma unroll
  for (int q = 0; q < 4; ++q) {
    float4 v = *(const float4*)(W + (size_t)(k0 + r) * 2048 + n0 + cg * 16 + q * 4);
    t[r][cg * 16 + q * 4 + 0] = v.x;
    t[r][cg * 16 + q * 4 + 1] = v.y;
    t[r][cg * 16 + q * 4 + 2] = v.z;
    t[r][cg * 16 + q * 4 + 3] = v.w;
  }
  __syncthreads();
  bf16x8 o0, o1;
#pragma unroll
  for (int j = 0; j < 8; ++j) o0[j] = (bf16_t)(t[cg * 16 + j][r] * scale);
#pragma unroll
  for (int j = 0; j < 8; ++j) o1[j] = (bf16_t)(t[cg * 16 + 8 + j][r] * scale);
  bf16_t* dst = WT + (size_t)(n0 + r) * 2048 + k0 + cg * 16;
  *(bf16x8*)dst = o0;
  *(bf16x8*)(dst + 8) = o1;
}

__global__ void lam_kernel(const float* lq1, const float* lk1,
                           const float* lq2, const float* lk2, float* out) {
  const int l = threadIdx.x;  // 64 threads
  float p1 = lq1[l] * lk1[l];
  float p2 = lq2[l] * lk2[l];
#pragma unroll
  for (int d = 1; d < 64; d <<= 1) {
    p1 += __shfl_xor(p1, d);
    p2 += __shfl_xor(p2, d);
  }
  if (l == 0) *out = expf(p1) - expf(p2) + LAMBDA_INIT;
}

// ---------------------------------------------------------------- gemm256
// 256x256 tile, BK=32, 512 threads (8 waves: wr=w>>2, wc=w&3), counted-vmcnt
// schedule: 4 LDS k-tile buffers (A 16K + B 16K each, 128KB dynamic), stage 3
// k-tiles ahead, vmcnt(8) once per k-tile (never 0 in steady state),
// raw s_barrier, setprio around MFMA clusters. N=4096 (QK merged); output
// dual bf16 row-major [4096][2048] mats split at global column 2048.
__global__ __launch_bounds__(512, 2) void gemm256(const bf16_t* __restrict__ A,
                                                  const bf16_t* __restrict__ Bt,
                                                  bf16_t* __restrict__ Cqk) {
  extern __shared__ __align__(16) char sm[];
  const int tid = threadIdx.x;
  const int w = tid >> 6, lane = tid & 63;
  const int wr = w >> 2, wc = w & 3;
  const int lm = lane >> 4, ln = lane & 15;
  const int nwg = (int)(gridDim.x * gridDim.y);
  const int flat = (int)blockIdx.y * (int)gridDim.x + (int)blockIdx.x;
  const int swz = (flat & 7) * (nwg >> 3) + (flat >> 3);  // bijective, nwg%8==0
  const int m0 = (swz & 15) * 256, n0 = (swz >> 4) * 256;

  int aoff[8], boff[4];
#pragma unroll
  for (int m = 0; m < 8; ++m) {
    const int row = wr * 128 + m * 16 + ln;
    aoff[m] = row * 64 + ((lm * 16) ^ ((((row >> 2) ^ row) & 3) << 4));
  }
#pragma unroll
  for (int n = 0; n < 4; ++n) {
    const int row = wc * 64 + n * 16 + ln;
    boff[n] = row * 64 + ((lm * 16) ^ ((((row >> 2) ^ row) & 3) << 4));
  }

  const bf16_t* gsrc[4];
  int ldst[4];
#pragma unroll
  for (int j = 0; j < 4; ++j) {
    const int r2 = j & 1, opB = j >> 1;
    const int row = r2 * 128 + w * 16 + (lane >> 2);
    const int colb = (lane & 3) * 16;
    const int cb = colb ^ ((((row >> 2) ^ row) & 3) << 4);
    gsrc[j] = (opB ? Bt + (size_t)(n0 + row) * 2048
                   : A + (size_t)(m0 + row) * 2048) + (cb >> 1);
    ldst[j] = opB * 16384 + r2 * 8192 + w * 1024;
  }

  const f32x4 vzero = {0.f, 0.f, 0.f, 0.f};
  f32x4 acc[8][4];
#pragma unroll
  for (int m = 0; m < 8; ++m)
#pragma unroll
    for (int n = 0; n < 4; ++n) acc[m][n] = vzero;

#pragma unroll
  for (int kt = 0; kt < 3; ++kt)
#pragma unroll
    for (int j = 0; j < 4; ++j)
      gload_lds16(gsrc[j] + kt * 32, sm + kt * 32768 + ldst[j]);
  asm volatile("s_waitcnt vmcnt(8)" ::: "memory");
  __builtin_amdgcn_s_barrier();

  for (int kt = 0; kt < 64; ++kt) {
    const char* sa = sm + (kt & 3) * 32768;
    const char* sb = sa + 16384;
    const int stage = kt + 3;
    char* sd = sm + (stage & 3) * 32768;
    bf16x8 bfr[4], af[4];

#pragma unroll
    for (int n = 0; n < 4; ++n) bfr[n] = *(const bf16x8*)(sb + boff[n]);
#pragma unroll
    for (int m = 0; m < 4; ++m) af[m] = *(const bf16x8*)(sa + aoff[m]);
    if (stage < 64) {
      gload_lds16(gsrc[0] + stage * 32, sd + ldst[0]);
      gload_lds16(gsrc[1] + stage * 32, sd + ldst[1]);
    }
    __builtin_amdgcn_s_barrier();
    __builtin_amdgcn_s_setprio(1);
#pragma unroll
    for (int m = 0; m < 4; ++m)
#pragma unroll
      for (int n = 0; n < 4; ++n) acc[m][n] = mfma_bf16(af[m], bfr[n], acc[m][n]);
    __builtin_amdgcn_s_setprio(0);
    __builtin_amdgcn_s_barrier();

#pragma unroll
    for (int m = 0; m < 4; ++m) af[m] = *(const bf16x8*)(sa + aoff[4 + m]);
    if (stage < 64) {
      gload_lds16(gsrc[2] + stage * 32, sd + ldst[2]);
      gload_lds16(gsrc[3] + stage * 32, sd + ldst[3]);
    }
    __builtin_amdgcn_s_barrier();
    __builtin_amdgcn_s_setprio(1);
#pragma unroll
    for (int m = 0; m < 4; ++m)
#pragma unroll
      for (int n = 0; n < 4; ++n)
        acc[4 + m][n] = mfma_bf16(af[m], bfr[n], acc[4 + m][n]);
    __builtin_amdgcn_s_setprio(0);
    if (kt < 61) {
      asm volatile("s_waitcnt vmcnt(8)" ::: "memory");
    } else if (kt == 61) {
      asm volatile("s_waitcnt vmcnt(4)" ::: "memory");
    } else if (kt == 62) {
      asm volatile("s_waitcnt vmcnt(0)" ::: "memory");
    }
    __builtin_amdgcn_s_barrier();
  }

  bf16_t* C = Cqk + (size_t)(n0 >> 11) * (4096u * 2048u);
#pragma unroll
  for (int m = 0; m < 8; ++m)
#pragma unroll
    for (int n = 0; n < 4; ++n)
#pragma unroll
      for (int r = 0; r < 4; ++r) {
        const size_t grow = m0 + wr * 128 + m * 16 + lm * 4 + r;
        const int gcol = (n0 + wc * 64 + n * 16 + ln) & 2047;
        C[grow * 2048 + gcol] = (bf16_t)acc[m][n][r];
      }
}

// ---------------------------------------------------------------- GEMM (128^2: V frag + O projection; R8-proven)
// OUTMODE 1: V-frag-ordered output; OUTMODE 2: f32 C row-major.
template <int OUTMODE>
__global__ __launch_bounds__(256, 2) void gemm_bt(const bf16_t* __restrict__ A,
                                                  const bf16_t* __restrict__ Bt,
                                                  void* __restrict__ Cv) {
  __shared__ __align__(16) bf16_t As[128 * 64];
  __shared__ __align__(16) bf16_t Bs[128 * 64];
  const int tid = threadIdx.x;
  const int w = tid >> 6, lane = tid & 63;
  const int wr = w >> 1, wc = w & 1;
  const int lm = lane >> 4, ln = lane & 15;
  const int nwg = (int)(gridDim.x * gridDim.y);
  const int flat = (int)blockIdx.y * (int)gridDim.x + (int)blockIdx.x;
  const int swz = (flat & 7) * (nwg >> 3) + (flat >> 3);
  const int m0 = (swz & 31) * 128, n0 = (swz >> 5) * 128;

  const f32x4 vzero = {0.f, 0.f, 0.f, 0.f};
  f32x4 acc[4][4];
#pragma unroll
  for (int m = 0; m < 4; ++m)
#pragma unroll
    for (int n = 0; n < 4; ++n) acc[m][n] = vzero;

  for (int k0 = 0; k0 < 2048; k0 += 64) {
    __syncthreads();
#pragma unroll
    for (int j = 0; j < 4; ++j) {
      const int inst = w * 4 + j;
      const int row = inst * 8 + (lane >> 3);
      const int cb = ((lane & 7) * 16) ^ ((row & 7) << 4);
      gload_lds16(A + (size_t)(m0 + row) * 2048 + k0 + (cb >> 1),
                  (char*)As + inst * 1024);
      gload_lds16(Bt + (size_t)(n0 + row) * 2048 + k0 + (cb >> 1),
                  (char*)Bs + inst * 1024);
    }
    asm volatile("s_waitcnt vmcnt(0)" ::: "memory");
    __syncthreads();

#pragma unroll
    for (int kc = 0; kc < 2; ++kc) {
      bf16x8 af[4], bfr[4];
#pragma unroll
      for (int m = 0; m < 4; ++m) {
        const int row = wr * 64 + m * 16 + ln;
        int off = row * 128 + kc * 64 + lm * 16;
        off ^= (row & 7) << 4;
        af[m] = *(const bf16x8*)((const char*)As + off);
      }
#pragma unroll
      for (int n = 0; n < 4; ++n) {
        const int row = wc * 64 + n * 16 + ln;
        int off = row * 128 + kc * 64 + lm * 16;
        off ^= (row & 7) << 4;
        bfr[n] = *(const bf16x8*)((const char*)Bs + off);
      }
      __builtin_amdgcn_s_setprio(1);
#pragma unroll
      for (int m = 0; m < 4; ++m)
#pragma unroll
        for (int n = 0; n < 4; ++n) acc[m][n] = mfma_bf16(af[m], bfr[n], acc[m][n]);
      __builtin_amdgcn_s_setprio(0);
    }
  }

  if (OUTMODE == 1) {
    bf16_t* C = (bf16_t*)Cv;  // frag-ordered V
#pragma unroll
    for (int m = 0; m < 4; ++m) {
      const int growb = m0 + wr * 64 + m * 16 + lm * 4;
      const int bb = growb >> 11, t = growb & 2047;
      const int kt = t >> 6, kk = (t >> 4) & 3, hi2 = (t >> 3) & 1, e0 = t & 7;
#pragma unroll
      for (int n = 0; n < 4; ++n) {
        const int gcol = n0 + wc * 64 + n * 16 + ln;
        const int hh = gcol >> 7, g = (gcol >> 5) & 3, l31o = gcol & 31;
        bf16x4 v;
#pragma unroll
        for (int r = 0; r < 4; ++r) v[r] = (bf16_t)acc[m][n][r];
        const size_t idx = ((size_t)((bb * 16 + hh) * 32 + kt)) * 8192 +
                           (size_t)(((g * 4 + kk) * 64 + hi2 * 32 + l31o) * 8 + e0);
        *(bf16x4*)(C + idx) = v;
      }
    }
  } else {
    float* C = (float*)Cv;
#pragma unroll
    for (int m = 0; m < 4; ++m)
#pragma unroll
      for (int n = 0; n < 4; ++n)
#pragma unroll
        for (int r = 0; r < 4; ++r) {
          const size_t grow = m0 + wr * 64 + m * 16 + lm * 4 + r;
          const int gcol = n0 + wc * 64 + n * 16 + ln;
          C[grow * 2048 + gcol] = acc[m][n][r];
        }
  }
}

// ---------------------------------------------------------------- flash diff-attn
// v9: 512 threads (8 waves = kh x s x qh). Fixed-max softmax is LINEAR in
// keys -> wave-group kh processes tiles kt%2==kh with NO rescaling; partial
// accv/lsum combined once per q-tile via LDS. Per-CU: 2 blocks x 8 waves =
// 16 waves (4/SIMD) at 64.5KB LDS -- doubles TLP vs R8 (grid capped 2 wv/SIMD).
// K per-group LDS dbuf (4x16KB); V direct from frag-ordered global; uniform
// 17 rounds/block via diagonal pairing.
__global__ __launch_bounds__(512, 2) void flash_diff(const bf16_t* __restrict__ Q,
                                                     const bf16_t* __restrict__ K,
                                                     const bf16_t* __restrict__ Vf,
                                                     bf16_t* __restrict__ attnb,
                                                     const float* __restrict__ lamP) {
  // [0,32K) kh=0 K dbuf; [32K,64K) kh=1 K dbuf. Epilogue overlays all 64KB.
  __shared__ __align__(16) char smem[65536];
  __shared__ float lsumb[2][64];  // [s][q] partial lsum from kh=1

  const int tid = threadIdx.x;
  const int w = tid >> 6, lane = tid & 63;
  const int kh = w & 1, s = (w >> 1) & 1, qh = w >> 2;
  const int wg = w >> 1;  // wave index within kh-group, [0,4)
  const int l31 = lane & 31, hi = lane >> 5;

  const int bid = (int)blockIdx.x;  // 0..511
  const int xcd = bid & 7, p = bid >> 3;
  const int qtp = p & 15, g2 = p >> 4;
  const int hb = g2 * 8 + xcd;      // all 16 qt-blocks of (h,b) on one XCD
  const int h = hb & 15, b = hb >> 4;
  const size_t bt0 = (size_t)b * 2048;
  const float lam = *lamP;

  f32x16 vz16;
#pragma unroll
  for (int r = 0; r < 16; ++r) vz16[r] = 0.f;
  asm volatile("" : "+v"(vz16));  // pin zero vector in registers

  auto stage_k = [&](int buf, int k0) {  // group kh's 4 waves stage 16KB
#pragma unroll
    for (int j = 0; j < 4; ++j) {
      const int inst = wg * 4 + j;
      const int row = inst * 4 + (lane >> 4);
      const int cb = ((lane & 15) * 16) ^ ((row & 15) << 4);
      gload_lds16(K + (bt0 + k0 + row) * 2048 + h * 128 + (cb >> 1),
                  smem + kh * 32768 + buf * 16384 + inst * 1024);
    }
  };

  for (int half = 0; half < 2; ++half) {
    const int qt = half == 0 ? qtp : 31 - qtp;
    const int q0 = qt * 64;
    const int qloc = qh * 32 + l31;

    bf16x8 qf[4];
#pragma unroll
    for (int kc = 0; kc < 4; ++kc)
      qf[kc] = *(const bf16x8*)(Q + (bt0 + q0 + qloc) * 2048 + h * 128 +
                                s * 64 + kc * 16 + hi * 8);

    if (kh <= qt) stage_k(0, kh * 64);
    asm volatile("s_waitcnt vmcnt(0)" ::: "memory");
    __syncthreads();

    f32x16 accv[4];
#pragma unroll
    for (int m = 0; m < 4; ++m) accv[m] = vz16;
    float lsum = 0.f;

    const int R = (qt >> 1) + 1;  // uniform across groups; total rounds/blk=17
    int cur = 0;
    for (int r = 0; r < R; ++r) {
      const int kt = 2 * r + kh;
      const bool active = kt <= qt;
      if (active && kt + 2 <= qt) stage_k(cur ^ 1, (kt + 2) * 64);

      if (active) {
        const char* Ksb = (const char*)smem + kh * 32768 + cur * 16384;
        const char* vsrc = (const char*)Vf +
                           (((size_t)((b * 16 + h) * 32 + kt)) << 14) + lane * 16;

        bf16x8 pf[2][2];
#pragma unroll
        for (int mt = 0; mt < 2; ++mt) {
          const int row = mt * 32 + l31;
          const int rswz = (row & 15) << 4;
          f32x16 sa;
          __builtin_amdgcn_s_setprio(1);
#pragma unroll
          for (int kc = 0; kc < 4; ++kc) {
            int off = row * 256 + s * 128 + kc * 32 + hi * 16;
            off ^= rswz;
            bf16x8 kf = *(const bf16x8*)(Ksb + off);
            sa = mfma32(kf, qf[kc], kc == 0 ? vz16 : sa);
          }
          __builtin_amdgcn_s_setprio(0);

          if (kt == qt) {  // causal mask within diagonal tile
#pragma unroll
            for (int r2 = 0; r2 < 16; ++r2) {
              const int key = mt * 32 + (r2 & 3) + 8 * (r2 >> 2) + 4 * hi;
              if (key > qloc) sa[r2] = -1e30f;
            }
          }
          float pv[16];
#pragma unroll
          for (int r2 = 0; r2 < 16; ++r2) {
            pv[r2] = exp2f(sa[r2]);
            lsum += pv[r2];
          }
          u32 c0 = pkbf(pv[0], pv[1]),   c1 = pkbf(pv[2], pv[3]);
          u32 c2 = pkbf(pv[4], pv[5]),   c3 = pkbf(pv[6], pv[7]);
          u32 c4 = pkbf(pv[8], pv[9]),   c5 = pkbf(pv[10], pv[11]);
          u32 c6 = pkbf(pv[12], pv[13]), c7 = pkbf(pv[14], pv[15]);
          pl32swap(c0, c2); pl32swap(c1, c3);
          pl32swap(c4, c6); pl32swap(c5, c7);
          union { u32 u[4]; bf16x8 v; } f0, f1;
          f0.u[0] = c0; f0.u[1] = c1; f0.u[2] = c2; f0.u[3] = c3;
          f1.u[0] = c4; f1.u[1] = c5; f1.u[2] = c6; f1.u[3] = c7;
          pf[mt][0] = f0.v;
          pf[mt][1] = f1.v;
        }

        // PV: V fragments direct from global (coalesced 1KB wave-loads)
#pragma unroll
        for (int g = 0; g < 4; ++g) {
          bf16x8 vf[4];
#pragma unroll
          for (int kk = 0; kk < 4; ++kk)
            vf[kk] = *(const bf16x8*)(vsrc + (g * 4 + kk) * 1024);
          __builtin_amdgcn_s_setprio(1);
#pragma unroll
          for (int kk = 0; kk < 4; ++kk)
            accv[g] = mfma32(vf[kk], pf[kk >> 1][kk & 1], accv[g]);
          __builtin_amdgcn_s_setprio(0);
        }
      }

      asm volatile("s_waitcnt vmcnt(0)" ::: "memory");
      __syncthreads();
      cur ^= 1;
    }

    // ---- epilogue: combine kh partials, then cross-s combine + RMS + store
    lsum += __shfl_xor(lsum, 32);

    if (kh == 1) {  // publish raw partials (K LDS dead)
      if (hi == 0) lsumb[s][qh * 32 + l31] = lsum;
      float* dst = (float*)(smem + (s * 2 + qh) * 16384) + l31 * 128;
#pragma unroll
      for (int mt4 = 0; mt4 < 4; ++mt4)
#pragma unroll
        for (int q2 = 0; q2 < 4; ++q2) {
          f32x4 v;
#pragma unroll
          for (int e = 0; e < 4; ++e) v[e] = accv[mt4][q2 * 4 + e];
          *(f32x4*)(dst + mt4 * 32 + q2 * 8 + hi * 4) = v;
        }
    }
    __syncthreads();

    float rl = 0.f;
    if (kh == 0) {  // absorb kh=1 partials
      lsum += lsumb[s][qh * 32 + l31];
      rl = 1.0f / lsum;
      const float* src = (const float*)(smem + (s * 2 + qh) * 16384) + l31 * 128;
#pragma unroll
      for (int mt4 = 0; mt4 < 4; ++mt4)
#pragma unroll
        for (int q2 = 0; q2 < 4; ++q2) {
          f32x4 v = *(const f32x4*)(src + mt4 * 32 + q2 * 8 + hi * 4);
#pragma unroll
          for (int e = 0; e < 4; ++e) accv[mt4][q2 * 4 + e] += v[e];
        }
    }
    __syncthreads();  // partial regions consumed; safe to overlay Obuf

    float* Obuf = (float*)smem;  // [64 q][128 d] f32 = 32KB
    if (kh == 0 && s == 1) {
#pragma unroll
      for (int mt4 = 0; mt4 < 4; ++mt4)
#pragma unroll
        for (int q2 = 0; q2 < 4; ++q2) {
          f32x4 v;
#pragma unroll
          for (int e = 0; e < 4; ++e) v[e] = accv[mt4][q2 * 4 + e] * rl;
          const int d = mt4 * 32 + q2 * 8 + hi * 4;
          *(f32x4*)(Obuf + (size_t)qloc * 128 + d) = v;
        }
    }
    __syncthreads();
    if (kh == 0 && s == 0) {
      float o[4][16];
      float ss = 0.f;
#pragma unroll
      for (int mt4 = 0; mt4 < 4; ++mt4)
#pragma unroll
        for (int q2 = 0; q2 < 4; ++q2) {
          const int d = mt4 * 32 + q2 * 8 + hi * 4;
          f32x4 ov = *(const f32x4*)(Obuf + (size_t)qloc * 128 + d);
#pragma unroll
          for (int e = 0; e < 4; ++e) {
            const float v = accv[mt4][q2 * 4 + e] * rl - lam * ov[e];
            o[mt4][q2 * 4 + e] = v;
            ss += v * v;
          }
        }
      ss += __shfl_xor(ss, 32);
      const float sc = rsqrtf(ss * (1.0f / 128.f) + 1e-5f) * ONE_MINUS_LAMBDA_INIT;
      const size_t grow = bt0 + q0 + qloc;
#pragma unroll
      for (int mt4 = 0; mt4 < 4; ++mt4)
#pragma unroll
        for (int q2 = 0; q2 < 4; ++q2) {
          const int d = mt4 * 32 + q2 * 8 + hi * 4;
          bf16x4 v;
#pragma unroll
          for (int e = 0; e < 4; ++e) v[e] = (bf16_t)(o[mt4][q2 * 4 + e] * sc);
          *(bf16x4*)(attnb + grow * 2048 + h * 128 + d) = v;
        }
    }
    __syncthreads();  // Obuf reads done before next half re-stages K
  }
}

// ---------------------------------------------------------------- launch
extern "C" void kernel_launch(void* const* d_in, const int* in_sizes, int n_in,
                              void* d_out, int out_size, void* d_ws, size_t ws_size,
                              hipStream_t stream) {
  const float* x   = (const float*)d_in[0];
  const float* Wq  = (const float*)d_in[1];
  const float* Wk  = (const float*)d_in[2];
  const float* Wv  = (const float*)d_in[3];
  const float* Wo  = (const float*)d_in[4];
  const float* lq1 = (const float*)d_in[5];
  const float* lk1 = (const float*)d_in[6];
  const float* lq2 = (const float*)d_in[7];
  const float* lk2 = (const float*)d_in[8];

  char* ws = (char*)d_ws;
  bf16_t* xb    = (bf16_t*)(ws + 0);                 // 16 MB [4096,2048]
  bf16_t* wqT   = (bf16_t*)(ws + 16777216);          // 8 MB (wkT contiguous after)
  bf16_t* wvT   = (bf16_t*)(ws + 33554432);          // 8 MB
  bf16_t* woT   = (bf16_t*)(ws + 41943040);          // 8 MB
  bf16_t* Qb    = (bf16_t*)(ws + 50331648);          // 16 MB (Kb contiguous)
  bf16_t* Kb    = (bf16_t*)(ws + 67108864);          // 16 MB
  bf16_t* Vfb   = (bf16_t*)(ws + 16777216);          // 16 MB frag-ordered V
                                                     //   (aliases wqT|wkT; written
                                                     //    only after QK GEMM done)
  bf16_t* attnb = (bf16_t*)(ws + 0);                 // aliases xb (dead then)
  float*  lamP  = (float*)(ws + 83886080);

  hipFuncSetAttribute((const void*)gemm256,
                      hipFuncAttributeMaxDynamicSharedMemorySize, 131072);

  cvt_bf16<<<4096, 256, 0, stream>>>(x, xb);
  WArgs wa;
  wa.W[0] = Wq; wa.W[1] = Wk; wa.W[2] = Wv; wa.W[3] = Wo;
  wa.WT[0] = wqT; wa.WT[1] = wqT + 4194304; wa.WT[2] = wvT; wa.WT[3] = woT;
  wa.sc[0] = 0.125f * L2E; wa.sc[1] = 1.0f; wa.sc[2] = 1.0f; wa.sc[3] = 1.0f;
  cvt_wT_all<<<dim3(32, 32, 4), 256, 0, stream>>>(wa);
  lam_kernel<<<1, 64, 0, stream>>>(lq1, lk1, lq2, lk2, lamP);

  // QK merged GEMM: N=4096 over contiguous wqT|wkT; 256 blocks = exact CU fill
  gemm256<<<dim3(16, 16), 512, 131072, stream>>>(xb, wqT, Qb);
  // V GEMM (frag-ordered out); Vfb aliases wqT|wkT, safe after gemm256
  gemm_bt<1><<<dim3(32, 16), 256, 0, stream>>>(xb, wvT, (void*)Vfb);

  flash_diff<<<512, 512, 0, stream>>>(Qb, Kb, Vfb, attnb, lamP);

  // O projection (f32 out, 128^2 tiles)
  gemm_bt<2><<<dim3(32, 16), 256, 0, stream>>>(attnb, woT, d_out);
}

// Round 16
// 261.267 us; speedup vs baseline: 1.1231x; 1.1231x over previous
//
#include <hip/hip_runtime.h>
#include <stdint.h>

typedef __bf16 bf16_t;
typedef __bf16 bf16x8 __attribute__((ext_vector_type(8)));
typedef __bf16 bf16x4 __attribute__((ext_vector_type(4)));
typedef float  f32x4  __attribute__((ext_vector_type(4)));
typedef float  f32x16 __attribute__((ext_vector_type(16)));
typedef unsigned int u32;

#define L2E 1.44269504088896340736f
#define LAMBDA_INIT 0.7836057665316245f
#define ONE_MINUS_LAMBDA_INIT 0.2163942334683755f

// ---------------------------------------------------------------- helpers
__device__ __forceinline__ void gload_lds16(const void* g, void* l) {
  __builtin_amdgcn_global_load_lds(
      (const __attribute__((address_space(1))) char*)(uintptr_t)g,
      (__attribute__((address_space(3))) char*)(uintptr_t)l, 16, 0, 0);
}

__device__ __forceinline__ f32x4 mfma_bf16(bf16x8 a, bf16x8 b, f32x4 c) {
  return __builtin_amdgcn_mfma_f32_16x16x32_bf16(a, b, c, 0, 0, 0);
}
__device__ __forceinline__ f32x16 mfma32(bf16x8 a, bf16x8 b, f32x16 c) {
  return __builtin_amdgcn_mfma_f32_32x32x16_bf16(a, b, c, 0, 0, 0);
}

__device__ __forceinline__ u32 pkbf(float a, float b) {
  union { bf16_t h[2]; u32 u; } x;
  x.h[0] = (bf16_t)a; x.h[1] = (bf16_t)b;
  return x.u;
}
__device__ __forceinline__ void pl32swap(u32& a, u32& b) {
  asm volatile("v_permlane32_swap_b32 %0, %1" : "+v"(a), "+v"(b));
}

// ---------------------------------------------------------------- conversions
__global__ __launch_bounds__(256) void cvt_bf16(const float* __restrict__ in,
                                                bf16_t* __restrict__ out) {
  const size_t idx = ((size_t)blockIdx.x * 256 + threadIdx.x) * 8;
  float4 a = *(const float4*)(in + idx);
  float4 c = *(const float4*)(in + idx + 4);
  bf16x8 v;
  v[0] = (bf16_t)a.x; v[1] = (bf16_t)a.y; v[2] = (bf16_t)a.z; v[3] = (bf16_t)a.w;
  v[4] = (bf16_t)c.x; v[5] = (bf16_t)c.y; v[6] = (bf16_t)c.z; v[7] = (bf16_t)c.w;
  *(bf16x8*)(out + idx) = v;
}

struct WArgs {
  const float* W[4];
  bf16_t* WT[4];
  float sc[4];
};

// W [2048,2048] f32 -> WT [2048,2048] bf16, WT[n][k] = W[k][n]*scale; 4 mats
__global__ __launch_bounds__(256) void cvt_wT_all(WArgs a) {
  __shared__ float t[64][65];
  const int i = blockIdx.z;
  const float* W = a.W[i];
  bf16_t* WT = a.WT[i];
  const float scale = a.sc[i];
  const int k0 = blockIdx.x * 64, n0 = blockIdx.y * 64;
  const int r = threadIdx.x >> 2, cg = threadIdx.x & 3;
#pragma unroll
  for (int q = 0; q < 4; ++q) {
    float4 v = *(const float4*)(W + (size_t)(k0 + r) * 2048 + n0 + cg * 16 + q * 4);
    t[r][cg * 16 + q * 4 + 0] = v.x;
    t[r][cg * 16 + q * 4 + 1] = v.y;
    t[r][cg * 16 + q * 4 + 2] = v.z;
    t[r][cg * 16 + q * 4 + 3] = v.w;
  }
  __syncthreads();
  bf16x8 o0, o1;
#pragma unroll
  for (int j = 0; j < 8; ++j) o0[j] = (bf16_t)(t[cg * 16 + j][r] * scale);
#pragma unroll
  for (int j = 0; j < 8; ++j) o1[j] = (bf16_t)(t[cg * 16 + 8 + j][r] * scale);
  bf16_t* dst = WT + (size_t)(n0 + r) * 2048 + k0 + cg * 16;
  *(bf16x8*)dst = o0;
  *(bf16x8*)(dst + 8) = o1;
}

__global__ void lam_kernel(const float* lq1, const float* lk1,
                           const float* lq2, const float* lk2, float* out) {
  const int l = threadIdx.x;  // 64 threads
  float p1 = lq1[l] * lk1[l];
  float p2 = lq2[l] * lk2[l];
#pragma unroll
  for (int d = 1; d < 64; d <<= 1) {
    p1 += __shfl_xor(p1, d);
    p2 += __shfl_xor(p2, d);
  }
  if (l == 0) *out = expf(p1) - expf(p2) + LAMBDA_INIT;
}

// ---------------------------------------------------------------- gemm256
// 256x256 tile, BK=32, 512 threads (8 waves: wr=w>>2, wc=w&3), counted-vmcnt
// schedule: 4 LDS k-tile buffers (A 16K + B 16K each, 128KB dynamic), stage 3
// k-tiles ahead, vmcnt(8) once per k-tile (never 0 in steady state),
// raw s_barrier, setprio around MFMA clusters. N=4096 (QK merged); output
// dual bf16 row-major [4096][2048] mats split at global column 2048.
__global__ __launch_bounds__(512, 2) void gemm256(const bf16_t* __restrict__ A,
                                                  const bf16_t* __restrict__ Bt,
                                                  bf16_t* __restrict__ Cqk) {
  extern __shared__ __align__(16) char sm[];
  const int tid = threadIdx.x;
  const int w = tid >> 6, lane = tid & 63;
  const int wr = w >> 2, wc = w & 3;
  const int lm = lane >> 4, ln = lane & 15;
  const int nwg = (int)(gridDim.x * gridDim.y);
  const int flat = (int)blockIdx.y * (int)gridDim.x + (int)blockIdx.x;
  const int swz = (flat & 7) * (nwg >> 3) + (flat >> 3);  // bijective, nwg%8==0
  const int m0 = (swz & 15) * 256, n0 = (swz >> 4) * 256;

  int aoff[8], boff[4];
#pragma unroll
  for (int m = 0; m < 8; ++m) {
    const int row = wr * 128 + m * 16 + ln;
    aoff[m] = row * 64 + ((lm * 16) ^ ((((row >> 2) ^ row) & 3) << 4));
  }
#pragma unroll
  for (int n = 0; n < 4; ++n) {
    const int row = wc * 64 + n * 16 + ln;
    boff[n] = row * 64 + ((lm * 16) ^ ((((row >> 2) ^ row) & 3) << 4));
  }

  const bf16_t* gsrc[4];
  int ldst[4];
#pragma unroll
  for (int j = 0; j < 4; ++j) {
    const int r2 = j & 1, opB = j >> 1;
    const int row = r2 * 128 + w * 16 + (lane >> 2);
    const int colb = (lane & 3) * 16;
    const int cb = colb ^ ((((row >> 2) ^ row) & 3) << 4);
    gsrc[j] = (opB ? Bt + (size_t)(n0 + row) * 2048
                   : A + (size_t)(m0 + row) * 2048) + (cb >> 1);
    ldst[j] = opB * 16384 + r2 * 8192 + w * 1024;
  }

  const f32x4 vzero = {0.f, 0.f, 0.f, 0.f};
  f32x4 acc[8][4];
#pragma unroll
  for (int m = 0; m < 8; ++m)
#pragma unroll
    for (int n = 0; n < 4; ++n) acc[m][n] = vzero;

#pragma unroll
  for (int kt = 0; kt < 3; ++kt)
#pragma unroll
    for (int j = 0; j < 4; ++j)
      gload_lds16(gsrc[j] + kt * 32, sm + kt * 32768 + ldst[j]);
  asm volatile("s_waitcnt vmcnt(8)" ::: "memory");
  __builtin_amdgcn_s_barrier();

  for (int kt = 0; kt < 64; ++kt) {
    const char* sa = sm + (kt & 3) * 32768;
    const char* sb = sa + 16384;
    const int stage = kt + 3;
    char* sd = sm + (stage & 3) * 32768;
    bf16x8 bfr[4], af[4];

#pragma unroll
    for (int n = 0; n < 4; ++n) bfr[n] = *(const bf16x8*)(sb + boff[n]);
#pragma unroll
    for (int m = 0; m < 4; ++m) af[m] = *(const bf16x8*)(sa + aoff[m]);
    if (stage < 64) {
      gload_lds16(gsrc[0] + stage * 32, sd + ldst[0]);
      gload_lds16(gsrc[1] + stage * 32, sd + ldst[1]);
    }
    __builtin_amdgcn_s_barrier();
    __builtin_amdgcn_s_setprio(1);
#pragma unroll
    for (int m = 0; m < 4; ++m)
#pragma unroll
      for (int n = 0; n < 4; ++n) acc[m][n] = mfma_bf16(af[m], bfr[n], acc[m][n]);
    __builtin_amdgcn_s_setprio(0);
    __builtin_amdgcn_s_barrier();

#pragma unroll
    for (int m = 0; m < 4; ++m) af[m] = *(const bf16x8*)(sa + aoff[4 + m]);
    if (stage < 64) {
      gload_lds16(gsrc[2] + stage * 32, sd + ldst[2]);
      gload_lds16(gsrc[3] + stage * 32, sd + ldst[3]);
    }
    __builtin_amdgcn_s_barrier();
    __builtin_amdgcn_s_setprio(1);
#pragma unroll
    for (int m = 0; m < 4; ++m)
#pragma unroll
      for (int n = 0; n < 4; ++n)
        acc[4 + m][n] = mfma_bf16(af[m], bfr[n], acc[4 + m][n]);
    __builtin_amdgcn_s_setprio(0);
    if (kt < 61) {
      asm volatile("s_waitcnt vmcnt(8)" ::: "memory");
    } else if (kt == 61) {
      asm volatile("s_waitcnt vmcnt(4)" ::: "memory");
    } else if (kt == 62) {
      asm volatile("s_waitcnt vmcnt(0)" ::: "memory");
    }
    __builtin_amdgcn_s_barrier();
  }

  bf16_t* C = Cqk + (size_t)(n0 >> 11) * (4096u * 2048u);
#pragma unroll
  for (int m = 0; m < 8; ++m)
#pragma unroll
    for (int n = 0; n < 4; ++n)
#pragma unroll
      for (int r = 0; r < 4; ++r) {
        const size_t grow = m0 + wr * 128 + m * 16 + lm * 4 + r;
        const int gcol = (n0 + wc * 64 + n * 16 + ln) & 2047;
        C[grow * 2048 + gcol] = (bf16_t)acc[m][n][r];
      }
}

// ---------------------------------------------------------------- GEMM (128^2: V frag + O projection; R8-proven)
// OUTMODE 1: V-frag-ordered output; OUTMODE 2: f32 C row-major.
template <int OUTMODE>
__global__ __launch_bounds__(256, 2) void gemm_bt(const bf16_t* __restrict__ A,
                                                  const bf16_t* __restrict__ Bt,
                                                  void* __restrict__ Cv) {
  __shared__ __align__(16) bf16_t As[128 * 64];
  __shared__ __align__(16) bf16_t Bs[128 * 64];
  const int tid = threadIdx.x;
  const int w = tid >> 6, lane = tid & 63;
  const int wr = w >> 1, wc = w & 1;
  const int lm = lane >> 4, ln = lane & 15;
  const int nwg = (int)(gridDim.x * gridDim.y);
  const int flat = (int)blockIdx.y * (int)gridDim.x + (int)blockIdx.x;
  const int swz = (flat & 7) * (nwg >> 3) + (flat >> 3);
  const int m0 = (swz & 31) * 128, n0 = (swz >> 5) * 128;

  const f32x4 vzero = {0.f, 0.f, 0.f, 0.f};
  f32x4 acc[4][4];
#pragma unroll
  for (int m = 0; m < 4; ++m)
#pragma unroll
    for (int n = 0; n < 4; ++n) acc[m][n] = vzero;

  for (int k0 = 0; k0 < 2048; k0 += 64) {
    __syncthreads();
#pragma unroll
    for (int j = 0; j < 4; ++j) {
      const int inst = w * 4 + j;
      const int row = inst * 8 + (lane >> 3);
      const int cb = ((lane & 7) * 16) ^ ((row & 7) << 4);
      gload_lds16(A + (size_t)(m0 + row) * 2048 + k0 + (cb >> 1),
                  (char*)As + inst * 1024);
      gload_lds16(Bt + (size_t)(n0 + row) * 2048 + k0 + (cb >> 1),
                  (char*)Bs + inst * 1024);
    }
    asm volatile("s_waitcnt vmcnt(0)" ::: "memory");
    __syncthreads();

#pragma unroll
    for (int kc = 0; kc < 2; ++kc) {
      bf16x8 af[4], bfr[4];
#pragma unroll
      for (int m = 0; m < 4; ++m) {
        const int row = wr * 64 + m * 16 + ln;
        int off = row * 128 + kc * 64 + lm * 16;
        off ^= (row & 7) << 4;
        af[m] = *(const bf16x8*)((const char*)As + off);
      }
#pragma unroll
      for (int n = 0; n < 4; ++n) {
        const int row = wc * 64 + n * 16 + ln;
        int off = row * 128 + kc * 64 + lm * 16;
        off ^= (row & 7) << 4;
        bfr[n] = *(const bf16x8*)((const char*)Bs + off);
      }
      __builtin_amdgcn_s_setprio(1);
#pragma unroll
      for (int m = 0; m < 4; ++m)
#pragma unroll
        for (int n = 0; n < 4; ++n) acc[m][n] = mfma_bf16(af[m], bfr[n], acc[m][n]);
      __builtin_amdgcn_s_setprio(0);
    }
  }

  if (OUTMODE == 1) {
    bf16_t* C = (bf16_t*)Cv;  // frag-ordered V
#pragma unroll
    for (int m = 0; m < 4; ++m) {
      const int growb = m0 + wr * 64 + m * 16 + lm * 4;
      const int bb = growb >> 11, t = growb & 2047;
      const int kt = t >> 6, kk = (t >> 4) & 3, hi2 = (t >> 3) & 1, e0 = t & 7;
#pragma unroll
      for (int n = 0; n < 4; ++n) {
        const int gcol = n0 + wc * 64 + n * 16 + ln;
        const int hh = gcol >> 7, g = (gcol >> 5) & 3, l31o = gcol & 31;
        bf16x4 v;
#pragma unroll
        for (int r = 0; r < 4; ++r) v[r] = (bf16_t)acc[m][n][r];
        const size_t idx = ((size_t)((bb * 16 + hh) * 32 + kt)) * 8192 +
                           (size_t)(((g * 4 + kk) * 64 + hi2 * 32 + l31o) * 8 + e0);
        *(bf16x4*)(C + idx) = v;
      }
    }
  } else {
    float* C = (float*)Cv;
#pragma unroll
    for (int m = 0; m < 4; ++m)
#pragma unroll
      for (int n = 0; n < 4; ++n)
#pragma unroll
        for (int r = 0; r < 4; ++r) {
          const size_t grow = m0 + wr * 64 + m * 16 + lm * 4 + r;
          const int gcol = n0 + wc * 64 + n * 16 + ln;
          C[grow * 2048 + gcol] = acc[m][n][r];
        }
  }
}

// ---------------------------------------------------------------- flash diff-attn
// R14 configuration (measured best). K in LDS dbuf [0,32K); V in LDS dbuf
// [32K,64K) staged from frag-ordered global (linear DMA + conflict-free
// lane*16 ds_read_b128). 512 blocks, diagonal-paired halves (uniform 33
// iters AND uniform duration per block), (h,b)-per-XCD grouping.
// T12 in-register P^T assembly; QK accumulators seeded from pinned zero reg.
__global__ __launch_bounds__(256, 2) void flash_diff(const bf16_t* __restrict__ Q,
                                                     const bf16_t* __restrict__ K,
                                                     const bf16_t* __restrict__ Vf,
                                                     bf16_t* __restrict__ attnb,
                                                     const float* __restrict__ lamP) {
  __shared__ __align__(16) char smem[65536];

  const int tid = threadIdx.x;
  const int w = tid >> 6, lane = tid & 63;
  const int qh = w >> 1, s = w & 1;
  const int l31 = lane & 31, hi = lane >> 5;

  const int bid = (int)blockIdx.x;  // 0..511
  const int xcd = bid & 7, p = bid >> 3;
  const int qtp = p & 15, g2 = p >> 4;
  const int hb = g2 * 8 + xcd;      // all 16 qt-blocks of (h,b) on one XCD
  const int h = hb & 15, b = hb >> 4;
  const size_t bt0 = (size_t)b * 2048;
  const float lam = *lamP;

  f32x16 vz16;
#pragma unroll
  for (int r = 0; r < 16; ++r) vz16[r] = 0.f;
  asm volatile("" : "+v"(vz16));  // pin: keep as live registers, not remat

  auto stage_k = [&](int buf, int k0) {
#pragma unroll
    for (int j = 0; j < 4; ++j) {
      const int inst = w * 4 + j;
      const int row = inst * 4 + (lane >> 4);
      const int cb = ((lane & 15) * 16) ^ ((row & 15) << 4);
      gload_lds16(K + (bt0 + k0 + row) * 2048 + h * 128 + (cb >> 1),
                  smem + buf * 16384 + inst * 1024);
    }
  };
  auto stage_v = [&](int buf, int kt) {
    const char* src = (const char*)Vf +
                      (((size_t)((b * 16 + h) * 32 + kt)) << 14) + lane * 16;
#pragma unroll
    for (int j = 0; j < 4; ++j) {
      const int inst = w * 4 + j;
      gload_lds16(src + inst * 1024, smem + 32768 + buf * 16384 + inst * 1024);
    }
  };

  for (int half = 0; half < 2; ++half) {
    const int qt = half == 0 ? qtp : 31 - qtp;
    const int q0 = qt * 64;
    const int qloc = qh * 32 + l31;

    bf16x8 qf[4];
#pragma unroll
    for (int kc = 0; kc < 4; ++kc)
      qf[kc] = *(const bf16x8*)(Q + (bt0 + q0 + qloc) * 2048 + h * 128 +
                                s * 64 + kc * 16 + hi * 8);

    stage_k(0, 0);
    stage_v(0, 0);
    asm volatile("s_waitcnt vmcnt(0)" ::: "memory");
    __syncthreads();

    f32x16 accv[4];
#pragma unroll
    for (int m = 0; m < 4; ++m) accv[m] = vz16;
    float lsum = 0.f;

    int cur = 0;
    for (int kt = 0; kt <= qt; ++kt) {
      if (kt < qt) {
        stage_k(cur ^ 1, (kt + 1) * 64);
        stage_v(cur ^ 1, kt + 1);
      }
      const char* Ksb = (const char*)smem + cur * 16384;
      const char* Vsb = (const char*)smem + 32768 + cur * 16384;

      bf16x8 pf[2][2];
#pragma unroll
      for (int mt = 0; mt < 2; ++mt) {
        const int row = mt * 32 + l31;
        const int rswz = (row & 15) << 4;
        f32x16 sa;
        __builtin_amdgcn_s_setprio(1);
#pragma unroll
        for (int kc = 0; kc < 4; ++kc) {
          int off = row * 256 + s * 128 + kc * 32 + hi * 16;
          off ^= rswz;
          bf16x8 kf = *(const bf16x8*)(Ksb + off);
          sa = mfma32(kf, qf[kc], kc == 0 ? vz16 : sa);  // seed from zero reg
        }
        __builtin_amdgcn_s_setprio(0);

        if (kt == qt) {
#pragma unroll
          for (int r = 0; r < 16; ++r) {
            const int key = mt * 32 + (r & 3) + 8 * (r >> 2) + 4 * hi;
            if (key > qloc) sa[r] = -1e30f;
          }
        }
        float pv[16];
#pragma unroll
        for (int r = 0; r < 16; ++r) {
          pv[r] = exp2f(sa[r]);
          lsum += pv[r];
        }
        u32 c0 = pkbf(pv[0], pv[1]),   c1 = pkbf(pv[2], pv[3]);
        u32 c2 = pkbf(pv[4], pv[5]),   c3 = pkbf(pv[6], pv[7]);
        u32 c4 = pkbf(pv[8], pv[9]),   c5 = pkbf(pv[10], pv[11]);
        u32 c6 = pkbf(pv[12], pv[13]), c7 = pkbf(pv[14], pv[15]);
        pl32swap(c0, c2); pl32swap(c1, c3);
        pl32swap(c4, c6); pl32swap(c5, c7);
        union { u32 u[4]; bf16x8 v; } f0, f1;
        f0.u[0] = c0; f0.u[1] = c1; f0.u[2] = c2; f0.u[3] = c3;
        f1.u[0] = c4; f1.u[1] = c5; f1.u[2] = c6; f1.u[3] = c7;
        pf[mt][0] = f0.v;
        pf[mt][1] = f1.v;
      }

#pragma unroll
      for (int g = 0; g < 4; ++g) {
        __builtin_amdgcn_s_setprio(1);
#pragma unroll
        for (int kk = 0; kk < 4; ++kk) {
          bf16x8 vfr = *(const bf16x8*)(Vsb + (g * 4 + kk) * 1024 + lane * 16);
          accv[g] = mfma32(vfr, pf[kk >> 1][kk & 1], accv[g]);
        }
        __builtin_amdgcn_s_setprio(0);
      }

      asm volatile("s_waitcnt vmcnt(0)" ::: "memory");
      __syncthreads();
      cur ^= 1;
    }

    lsum += __shfl_xor(lsum, 32);
    const float rl = 1.0f / lsum;
    float* Obuf = (float*)smem;

    if (s == 1) {
#pragma unroll
      for (int mt4 = 0; mt4 < 4; ++mt4)
#pragma unroll
        for (int q2 = 0; q2 < 4; ++q2) {
          f32x4 v;
#pragma unroll
          for (int e = 0; e < 4; ++e) v[e] = accv[mt4][q2 * 4 + e] * rl;
          const int d = mt4 * 32 + q2 * 8 + hi * 4;
          *(f32x4*)(Obuf + (size_t)qloc * 128 + d) = v;
        }
    }
    __syncthreads();
    if (s == 0) {
      float o[4][16];
      float ss = 0.f;
#pragma unroll
      for (int mt4 = 0; mt4 < 4; ++mt4)
#pragma unroll
        for (int q2 = 0; q2 < 4; ++q2) {
          const int d = mt4 * 32 + q2 * 8 + hi * 4;
          f32x4 ov = *(const f32x4*)(Obuf + (size_t)qloc * 128 + d);
#pragma unroll
          for (int e = 0; e < 4; ++e) {
            const float v = accv[mt4][q2 * 4 + e] * rl - lam * ov[e];
            o[mt4][q2 * 4 + e] = v;
            ss += v * v;
          }
        }
      ss += __shfl_xor(ss, 32);
      const float sc = rsqrtf(ss * (1.0f / 128.f) + 1e-5f) * ONE_MINUS_LAMBDA_INIT;
      const size_t grow = bt0 + q0 + qloc;
#pragma unroll
      for (int mt4 = 0; mt4 < 4; ++mt4)
#pragma unroll
        for (int q2 = 0; q2 < 4; ++q2) {
          const int d = mt4 * 32 + q2 * 8 + hi * 4;
          bf16x4 v;
#pragma unroll
          for (int e = 0; e < 4; ++e) v[e] = (bf16_t)(o[mt4][q2 * 4 + e] * sc);
          *(bf16x4*)(attnb + grow * 2048 + h * 128 + d) = v;
        }
    }
    __syncthreads();  // Obuf reads done before next half re-stages K
  }
}

// ---------------------------------------------------------------- launch
extern "C" void kernel_launch(void* const* d_in, const int* in_sizes, int n_in,
                              void* d_out, int out_size, void* d_ws, size_t ws_size,
                              hipStream_t stream) {
  const float* x   = (const float*)d_in[0];
  const float* Wq  = (const float*)d_in[1];
  const float* Wk  = (const float*)d_in[2];
  const float* Wv  = (const float*)d_in[3];
  const float* Wo  = (const float*)d_in[4];
  const float* lq1 = (const float*)d_in[5];
  const float* lk1 = (const float*)d_in[6];
  const float* lq2 = (const float*)d_in[7];
  const float* lk2 = (const float*)d_in[8];

  char* ws = (char*)d_ws;
  bf16_t* xb    = (bf16_t*)(ws + 0);                 // 16 MB [4096,2048]
  bf16_t* wqT   = (bf16_t*)(ws + 16777216);          // 8 MB (wkT contiguous after)
  bf16_t* wvT   = (bf16_t*)(ws + 33554432);          // 8 MB
  bf16_t* woT   = (bf16_t*)(ws + 41943040);          // 8 MB
  bf16_t* Qb    = (bf16_t*)(ws + 50331648);          // 16 MB (Kb contiguous)
  bf16_t* Kb    = (bf16_t*)(ws + 67108864);          // 16 MB
  bf16_t* Vfb   = (bf16_t*)(ws + 16777216);          // 16 MB frag-ordered V
                                                     //   (aliases wqT|wkT; written
                                                     //    only after QK GEMM done)
  bf16_t* attnb = (bf16_t*)(ws + 0);                 // aliases xb (dead then)
  float*  lamP  = (float*)(ws + 83886080);

  hipFuncSetAttribute((const void*)gemm256,
                      hipFuncAttributeMaxDynamicSharedMemorySize, 131072);

  cvt_bf16<<<4096, 256, 0, stream>>>(x, xb);
  WArgs wa;
  wa.W[0] = Wq; wa.W[1] = Wk; wa.W[2] = Wv; wa.W[3] = Wo;
  wa.WT[0] = wqT; wa.WT[1] = wqT + 4194304; wa.WT[2] = wvT; wa.WT[3] = woT;
  wa.sc[0] = 0.125f * L2E; wa.sc[1] = 1.0f; wa.sc[2] = 1.0f; wa.sc[3] = 1.0f;
  cvt_wT_all<<<dim3(32, 32, 4), 256, 0, stream>>>(wa);
  lam_kernel<<<1, 64, 0, stream>>>(lq1, lk1, lq2, lk2, lamP);

  // QK merged GEMM: N=4096 over contiguous wqT|wkT; 256 blocks = exact CU fill
  gemm256<<<dim3(16, 16), 512, 131072, stream>>>(xb, wqT, Qb);
  // V GEMM (frag-ordered out); Vfb aliases wqT|wkT, safe after gemm256
  gemm_bt<1><<<dim3(32, 16), 256, 0, stream>>>(xb, wvT, (void*)Vfb);

  flash_diff<<<512, 256, 0, stream>>>(Qb, Kb, Vfb, attnb, lamP);

  // O projection (f32 out, 128^2 tiles)
  gemm_bt<2><<<dim3(32, 16), 256, 0, stream>>>(attnb, woT, d_out);
}

// Round 17
// 256.080 us; speedup vs baseline: 1.1458x; 1.0203x over previous
//
#include <hip/hip_runtime.h>
#include <stdint.h>

typedef __bf16 bf16_t;
typedef __bf16 bf16x8 __attribute__((ext_vector_type(8)));
typedef __bf16 bf16x4 __attribute__((ext_vector_type(4)));
typedef float  f32x4  __attribute__((ext_vector_type(4)));
typedef float  f32x16 __attribute__((ext_vector_type(16)));
typedef unsigned int u32;

#define L2E 1.44269504088896340736f
#define LAMBDA_INIT 0.7836057665316245f
#define ONE_MINUS_LAMBDA_INIT 0.2163942334683755f

// ---------------------------------------------------------------- helpers
__device__ __forceinline__ void gload_lds16(const void* g, void* l) {
  __builtin_amdgcn_global_load_lds(
      (const __attribute__((address_space(1))) char*)(uintptr_t)g,
      (__attribute__((address_space(3))) char*)(uintptr_t)l, 16, 0, 0);
}

__device__ __forceinline__ f32x4 mfma_bf16(bf16x8 a, bf16x8 b, f32x4 c) {
  return __builtin_amdgcn_mfma_f32_16x16x32_bf16(a, b, c, 0, 0, 0);
}
__device__ __forceinline__ f32x16 mfma32(bf16x8 a, bf16x8 b, f32x16 c) {
  return __builtin_amdgcn_mfma_f32_32x32x16_bf16(a, b, c, 0, 0, 0);
}

__device__ __forceinline__ u32 pkbf(float a, float b) {
  union { bf16_t h[2]; u32 u; } x;
  x.h[0] = (bf16_t)a; x.h[1] = (bf16_t)b;
  return x.u;
}
__device__ __forceinline__ void pl32swap(u32& a, u32& b) {
  asm volatile("v_permlane32_swap_b32 %0, %1" : "+v"(a), "+v"(b));
}

// ---------------------------------------------------------------- fused prologue
// One dispatch replaces cvt_bf16 (4096 blocks) + cvt_wT_all (4096) + lam (1):
//   bid < 4096        : x f32 -> bf16 (2048 elems/block)
//   4096 <= bid < 8192: W transpose 64x64 tile, WT[n][k] = W[k][n]*scale
//   bid == 8192       : lambda scalar (wave 0 only)
struct PrepArgs {
  const float* x;
  bf16_t* xb;
  const float* W[4];
  bf16_t* WT[4];
  float sc[4];
  const float *lq1, *lk1, *lq2, *lk2;
  float* lam;
};

__global__ __launch_bounds__(256) void prep(PrepArgs a) {
  __shared__ float t[64][65];
  const int bid = (int)blockIdx.x;
  const int tid = threadIdx.x;

  if (bid < 4096) {  // ---- x -> bf16
    const size_t idx = ((size_t)bid * 256 + tid) * 8;
    float4 v0 = *(const float4*)(a.x + idx);
    float4 v1 = *(const float4*)(a.x + idx + 4);
    bf16x8 v;
    v[0] = (bf16_t)v0.x; v[1] = (bf16_t)v0.y; v[2] = (bf16_t)v0.z; v[3] = (bf16_t)v0.w;
    v[4] = (bf16_t)v1.x; v[5] = (bf16_t)v1.y; v[6] = (bf16_t)v1.z; v[7] = (bf16_t)v1.w;
    *(bf16x8*)(a.xb + idx) = v;
  } else if (bid < 8192) {  // ---- W transpose (4 mats x 1024 tiles)
    const int q = bid - 4096;
    const int i = q >> 10, rem = q & 1023;
    const float* W = a.W[i];
    bf16_t* WT = a.WT[i];
    const float scale = a.sc[i];
    const int k0 = (rem & 31) * 64, n0 = (rem >> 5) * 64;
    const int r = tid >> 2, cg = tid & 3;
#pragma unroll
    for (int qq = 0; qq < 4; ++qq) {
      float4 v = *(const float4*)(W + (size_t)(k0 + r) * 2048 + n0 + cg * 16 + qq * 4);
      t[r][cg * 16 + qq * 4 + 0] = v.x;
      t[r][cg * 16 + qq * 4 + 1] = v.y;
      t[r][cg * 16 + qq * 4 + 2] = v.z;
      t[r][cg * 16 + qq * 4 + 3] = v.w;
    }
    __syncthreads();
    bf16x8 o0, o1;
#pragma unroll
    for (int j = 0; j < 8; ++j) o0[j] = (bf16_t)(t[cg * 16 + j][r] * scale);
#pragma unroll
    for (int j = 0; j < 8; ++j) o1[j] = (bf16_t)(t[cg * 16 + 8 + j][r] * scale);
    bf16_t* dst = WT + (size_t)(n0 + r) * 2048 + k0 + cg * 16;
    *(bf16x8*)dst = o0;
    *(bf16x8*)(dst + 8) = o1;
  } else if (tid < 64) {  // ---- lambda
    float p1 = a.lq1[tid] * a.lk1[tid];
    float p2 = a.lq2[tid] * a.lk2[tid];
#pragma unroll
    for (int d = 1; d < 64; d <<= 1) {
      p1 += __shfl_xor(p1, d);
      p2 += __shfl_xor(p2, d);
    }
    if (tid == 0) *a.lam = expf(p1) - expf(p2) + LAMBDA_INIT;
  }
}

// ---------------------------------------------------------------- gemm256
// 256x256 tile, BK=32, 512 threads (8 waves: wr=w>>2, wc=w&3), counted-vmcnt
// schedule: 4 LDS k-tile buffers (A 16K + B 16K each, 128KB dynamic), stage 3
// k-tiles ahead, vmcnt(8) once per k-tile (never 0 in steady state),
// raw s_barrier, setprio around MFMA clusters. N=4096 (QK merged); output
// dual bf16 row-major [4096][2048] mats split at global column 2048.
__global__ __launch_bounds__(512, 2) void gemm256(const bf16_t* __restrict__ A,
                                                  const bf16_t* __restrict__ Bt,
                                                  bf16_t* __restrict__ Cqk) {
  extern __shared__ __align__(16) char sm[];
  const int tid = threadIdx.x;
  const int w = tid >> 6, lane = tid & 63;
  const int wr = w >> 2, wc = w & 3;
  const int lm = lane >> 4, ln = lane & 15;
  const int nwg = (int)(gridDim.x * gridDim.y);
  const int flat = (int)blockIdx.y * (int)gridDim.x + (int)blockIdx.x;
  const int swz = (flat & 7) * (nwg >> 3) + (flat >> 3);  // bijective, nwg%8==0
  const int m0 = (swz & 15) * 256, n0 = (swz >> 4) * 256;

  int aoff[8], boff[4];
#pragma unroll
  for (int m = 0; m < 8; ++m) {
    const int row = wr * 128 + m * 16 + ln;
    aoff[m] = row * 64 + ((lm * 16) ^ ((((row >> 2) ^ row) & 3) << 4));
  }
#pragma unroll
  for (int n = 0; n < 4; ++n) {
    const int row = wc * 64 + n * 16 + ln;
    boff[n] = row * 64 + ((lm * 16) ^ ((((row >> 2) ^ row) & 3) << 4));
  }

  const bf16_t* gsrc[4];
  int ldst[4];
#pragma unroll
  for (int j = 0; j < 4; ++j) {
    const int r2 = j & 1, opB = j >> 1;
    const int row = r2 * 128 + w * 16 + (lane >> 2);
    const int colb = (lane & 3) * 16;
    const int cb = colb ^ ((((row >> 2) ^ row) & 3) << 4);
    gsrc[j] = (opB ? Bt + (size_t)(n0 + row) * 2048
                   : A + (size_t)(m0 + row) * 2048) + (cb >> 1);
    ldst[j] = opB * 16384 + r2 * 8192 + w * 1024;
  }

  const f32x4 vzero = {0.f, 0.f, 0.f, 0.f};
  f32x4 acc[8][4];
#pragma unroll
  for (int m = 0; m < 8; ++m)
#pragma unroll
    for (int n = 0; n < 4; ++n) acc[m][n] = vzero;

#pragma unroll
  for (int kt = 0; kt < 3; ++kt)
#pragma unroll
    for (int j = 0; j < 4; ++j)
      gload_lds16(gsrc[j] + kt * 32, sm + kt * 32768 + ldst[j]);
  asm volatile("s_waitcnt vmcnt(8)" ::: "memory");
  __builtin_amdgcn_s_barrier();

  for (int kt = 0; kt < 64; ++kt) {
    const char* sa = sm + (kt & 3) * 32768;
    const char* sb = sa + 16384;
    const int stage = kt + 3;
    char* sd = sm + (stage & 3) * 32768;
    bf16x8 bfr[4], af[4];

#pragma unroll
    for (int n = 0; n < 4; ++n) bfr[n] = *(const bf16x8*)(sb + boff[n]);
#pragma unroll
    for (int m = 0; m < 4; ++m) af[m] = *(const bf16x8*)(sa + aoff[m]);
    if (stage < 64) {
      gload_lds16(gsrc[0] + stage * 32, sd + ldst[0]);
      gload_lds16(gsrc[1] + stage * 32, sd + ldst[1]);
    }
    __builtin_amdgcn_s_barrier();
    __builtin_amdgcn_s_setprio(1);
#pragma unroll
    for (int m = 0; m < 4; ++m)
#pragma unroll
      for (int n = 0; n < 4; ++n) acc[m][n] = mfma_bf16(af[m], bfr[n], acc[m][n]);
    __builtin_amdgcn_s_setprio(0);
    __builtin_amdgcn_s_barrier();

#pragma unroll
    for (int m = 0; m < 4; ++m) af[m] = *(const bf16x8*)(sa + aoff[4 + m]);
    if (stage < 64) {
      gload_lds16(gsrc[2] + stage * 32, sd + ldst[2]);
      gload_lds16(gsrc[3] + stage * 32, sd + ldst[3]);
    }
    __builtin_amdgcn_s_barrier();
    __builtin_amdgcn_s_setprio(1);
#pragma unroll
    for (int m = 0; m < 4; ++m)
#pragma unroll
      for (int n = 0; n < 4; ++n)
        acc[4 + m][n] = mfma_bf16(af[m], bfr[n], acc[4 + m][n]);
    __builtin_amdgcn_s_setprio(0);
    if (kt < 61) {
      asm volatile("s_waitcnt vmcnt(8)" ::: "memory");
    } else if (kt == 61) {
      asm volatile("s_waitcnt vmcnt(4)" ::: "memory");
    } else if (kt == 62) {
      asm volatile("s_waitcnt vmcnt(0)" ::: "memory");
    }
    __builtin_amdgcn_s_barrier();
  }

  bf16_t* C = Cqk + (size_t)(n0 >> 11) * (4096u * 2048u);
#pragma unroll
  for (int m = 0; m < 8; ++m)
#pragma unroll
    for (int n = 0; n < 4; ++n)
#pragma unroll
      for (int r = 0; r < 4; ++r) {
        const size_t grow = m0 + wr * 128 + m * 16 + lm * 4 + r;
        const int gcol = (n0 + wc * 64 + n * 16 + ln) & 2047;
        C[grow * 2048 + gcol] = (bf16_t)acc[m][n][r];
      }
}

// ---------------------------------------------------------------- GEMM (128^2: V frag + O projection; R8-proven)
// OUTMODE 1: V-frag-ordered output; OUTMODE 2: f32 C row-major.
template <int OUTMODE>
__global__ __launch_bounds__(256, 2) void gemm_bt(const bf16_t* __restrict__ A,
                                                  const bf16_t* __restrict__ Bt,
                                                  void* __restrict__ Cv) {
  __shared__ __align__(16) bf16_t As[128 * 64];
  __shared__ __align__(16) bf16_t Bs[128 * 64];
  const int tid = threadIdx.x;
  const int w = tid >> 6, lane = tid & 63;
  const int wr = w >> 1, wc = w & 1;
  const int lm = lane >> 4, ln = lane & 15;
  const int nwg = (int)(gridDim.x * gridDim.y);
  const int flat = (int)blockIdx.y * (int)gridDim.x + (int)blockIdx.x;
  const int swz = (flat & 7) * (nwg >> 3) + (flat >> 3);
  const int m0 = (swz & 31) * 128, n0 = (swz >> 5) * 128;

  const f32x4 vzero = {0.f, 0.f, 0.f, 0.f};
  f32x4 acc[4][4];
#pragma unroll
  for (int m = 0; m < 4; ++m)
#pragma unroll
    for (int n = 0; n < 4; ++n) acc[m][n] = vzero;

  for (int k0 = 0; k0 < 2048; k0 += 64) {
    __syncthreads();
#pragma unroll
    for (int j = 0; j < 4; ++j) {
      const int inst = w * 4 + j;
      const int row = inst * 8 + (lane >> 3);
      const int cb = ((lane & 7) * 16) ^ ((row & 7) << 4);
      gload_lds16(A + (size_t)(m0 + row) * 2048 + k0 + (cb >> 1),
                  (char*)As + inst * 1024);
      gload_lds16(Bt + (size_t)(n0 + row) * 2048 + k0 + (cb >> 1),
                  (char*)Bs + inst * 1024);
    }
    asm volatile("s_waitcnt vmcnt(0)" ::: "memory");
    __syncthreads();

#pragma unroll
    for (int kc = 0; kc < 2; ++kc) {
      bf16x8 af[4], bfr[4];
#pragma unroll
      for (int m = 0; m < 4; ++m) {
        const int row = wr * 64 + m * 16 + ln;
        int off = row * 128 + kc * 64 + lm * 16;
        off ^= (row & 7) << 4;
        af[m] = *(const bf16x8*)((const char*)As + off);
      }
#pragma unroll
      for (int n = 0; n < 4; ++n) {
        const int row = wc * 64 + n * 16 + ln;
        int off = row * 128 + kc * 64 + lm * 16;
        off ^= (row & 7) << 4;
        bfr[n] = *(const bf16x8*)((const char*)Bs + off);
      }
      __builtin_amdgcn_s_setprio(1);
#pragma unroll
      for (int m = 0; m < 4; ++m)
#pragma unroll
        for (int n = 0; n < 4; ++n) acc[m][n] = mfma_bf16(af[m], bfr[n], acc[m][n]);
      __builtin_amdgcn_s_setprio(0);
    }
  }

  if (OUTMODE == 1) {
    bf16_t* C = (bf16_t*)Cv;  // frag-ordered V
#pragma unroll
    for (int m = 0; m < 4; ++m) {
      const int growb = m0 + wr * 64 + m * 16 + lm * 4;
      const int bb = growb >> 11, t = growb & 2047;
      const int kt = t >> 6, kk = (t >> 4) & 3, hi2 = (t >> 3) & 1, e0 = t & 7;
#pragma unroll
      for (int n = 0; n < 4; ++n) {
        const int gcol = n0 + wc * 64 + n * 16 + ln;
        const int hh = gcol >> 7, g = (gcol >> 5) & 3, l31o = gcol & 31;
        bf16x4 v;
#pragma unroll
        for (int r = 0; r < 4; ++r) v[r] = (bf16_t)acc[m][n][r];
        const size_t idx = ((size_t)((bb * 16 + hh) * 32 + kt)) * 8192 +
                           (size_t)(((g * 4 + kk) * 64 + hi2 * 32 + l31o) * 8 + e0);
        *(bf16x4*)(C + idx) = v;
      }
    }
  } else {
    float* C = (float*)Cv;
#pragma unroll
    for (int m = 0; m < 4; ++m)
#pragma unroll
      for (int n = 0; n < 4; ++n)
#pragma unroll
        for (int r = 0; r < 4; ++r) {
          const size_t grow = m0 + wr * 64 + m * 16 + lm * 4 + r;
          const int gcol = n0 + wc * 64 + n * 16 + ln;
          C[grow * 2048 + gcol] = acc[m][n][r];
        }
  }
}

// ---------------------------------------------------------------- flash diff-attn
// R14 configuration (measured best). K in LDS dbuf [0,32K); V in LDS dbuf
// [32K,64K) staged from frag-ordered global (linear DMA + conflict-free
// lane*16 ds_read_b128). 512 blocks, diagonal-paired halves (uniform 33
// iters AND uniform duration per block), (h,b)-per-XCD grouping.
// T12 in-register P^T assembly; QK accumulators seeded from pinned zero reg.
__global__ __launch_bounds__(256, 2) void flash_diff(const bf16_t* __restrict__ Q,
                                                     const bf16_t* __restrict__ K,
                                                     const bf16_t* __restrict__ Vf,
                                                     bf16_t* __restrict__ attnb,
                                                     const float* __restrict__ lamP) {
  __shared__ __align__(16) char smem[65536];

  const int tid = threadIdx.x;
  const int w = tid >> 6, lane = tid & 63;
  const int qh = w >> 1, s = w & 1;
  const int l31 = lane & 31, hi = lane >> 5;

  const int bid = (int)blockIdx.x;  // 0..511
  const int xcd = bid & 7, p = bid >> 3;
  const int qtp = p & 15, g2 = p >> 4;
  const int hb = g2 * 8 + xcd;      // all 16 qt-blocks of (h,b) on one XCD
  const int h = hb & 15, b = hb >> 4;
  const size_t bt0 = (size_t)b * 2048;
  const float lam = *lamP;

  f32x16 vz16;
#pragma unroll
  for (int r = 0; r < 16; ++r) vz16[r] = 0.f;
  asm volatile("" : "+v"(vz16));  // pin: keep as live registers, not remat

  auto stage_k = [&](int buf, int k0) {
#pragma unroll
    for (int j = 0; j < 4; ++j) {
      const int inst = w * 4 + j;
      const int row = inst * 4 + (lane >> 4);
      const int cb = ((lane & 15) * 16) ^ ((row & 15) << 4);
      gload_lds16(K + (bt0 + k0 + row) * 2048 + h * 128 + (cb >> 1),
                  smem + buf * 16384 + inst * 1024);
    }
  };
  auto stage_v = [&](int buf, int kt) {
    const char* src = (const char*)Vf +
                      (((size_t)((b * 16 + h) * 32 + kt)) << 14) + lane * 16;
#pragma unroll
    for (int j = 0; j < 4; ++j) {
      const int inst = w * 4 + j;
      gload_lds16(src + inst * 1024, smem + 32768 + buf * 16384 + inst * 1024);
    }
  };

  for (int half = 0; half < 2; ++half) {
    const int qt = half == 0 ? qtp : 31 - qtp;
    const int q0 = qt * 64;
    const int qloc = qh * 32 + l31;

    bf16x8 qf[4];
#pragma unroll
    for (int kc = 0; kc < 4; ++kc)
      qf[kc] = *(const bf16x8*)(Q + (bt0 + q0 + qloc) * 2048 + h * 128 +
                                s * 64 + kc * 16 + hi * 8);

    stage_k(0, 0);
    stage_v(0, 0);
    asm volatile("s_waitcnt vmcnt(0)" ::: "memory");
    __syncthreads();

    f32x16 accv[4];
#pragma unroll
    for (int m = 0; m < 4; ++m) accv[m] = vz16;
    float lsum = 0.f;

    int cur = 0;
    for (int kt = 0; kt <= qt; ++kt) {
      if (kt < qt) {
        stage_k(cur ^ 1, (kt + 1) * 64);
        stage_v(cur ^ 1, kt + 1);
      }
      const char* Ksb = (const char*)smem + cur * 16384;
      const char* Vsb = (const char*)smem + 32768 + cur * 16384;

      bf16x8 pf[2][2];
#pragma unroll
      for (int mt = 0; mt < 2; ++mt) {
        const int row = mt * 32 + l31;
        const int rswz = (row & 15) << 4;
        f32x16 sa;
        __builtin_amdgcn_s_setprio(1);
#pragma unroll
        for (int kc = 0; kc < 4; ++kc) {
          int off = row * 256 + s * 128 + kc * 32 + hi * 16;
          off ^= rswz;
          bf16x8 kf = *(const bf16x8*)(Ksb + off);
          sa = mfma32(kf, qf[kc], kc == 0 ? vz16 : sa);  // seed from zero reg
        }
        __builtin_amdgcn_s_setprio(0);

        if (kt == qt) {
#pragma unroll
          for (int r = 0; r < 16; ++r) {
            const int key = mt * 32 + (r & 3) + 8 * (r >> 2) + 4 * hi;
            if (key > qloc) sa[r] = -1e30f;
          }
        }
        float pv[16];
#pragma unroll
        for (int r = 0; r < 16; ++r) {
          pv[r] = exp2f(sa[r]);
          lsum += pv[r];
        }
        u32 c0 = pkbf(pv[0], pv[1]),   c1 = pkbf(pv[2], pv[3]);
        u32 c2 = pkbf(pv[4], pv[5]),   c3 = pkbf(pv[6], pv[7]);
        u32 c4 = pkbf(pv[8], pv[9]),   c5 = pkbf(pv[10], pv[11]);
        u32 c6 = pkbf(pv[12], pv[13]), c7 = pkbf(pv[14], pv[15]);
        pl32swap(c0, c2); pl32swap(c1, c3);
        pl32swap(c4, c6); pl32swap(c5, c7);
        union { u32 u[4]; bf16x8 v; } f0, f1;
        f0.u[0] = c0; f0.u[1] = c1; f0.u[2] = c2; f0.u[3] = c3;
        f1.u[0] = c4; f1.u[1] = c5; f1.u[2] = c6; f1.u[3] = c7;
        pf[mt][0] = f0.v;
        pf[mt][1] = f1.v;
      }

#pragma unroll
      for (int g = 0; g < 4; ++g) {
        __builtin_amdgcn_s_setprio(1);
#pragma unroll
        for (int kk = 0; kk < 4; ++kk) {
          bf16x8 vfr = *(const bf16x8*)(Vsb + (g * 4 + kk) * 1024 + lane * 16);
          accv[g] = mfma32(vfr, pf[kk >> 1][kk & 1], accv[g]);
        }
        __builtin_amdgcn_s_setprio(0);
      }

      asm volatile("s_waitcnt vmcnt(0)" ::: "memory");
      __syncthreads();
      cur ^= 1;
    }

    lsum += __shfl_xor(lsum, 32);
    const float rl = 1.0f / lsum;
    float* Obuf = (float*)smem;

    if (s == 1) {
#pragma unroll
      for (int mt4 = 0; mt4 < 4; ++mt4)
#pragma unroll
        for (int q2 = 0; q2 < 4; ++q2) {
          f32x4 v;
#pragma unroll
          for (int e = 0; e < 4; ++e) v[e] = accv[mt4][q2 * 4 + e] * rl;
          const int d = mt4 * 32 + q2 * 8 + hi * 4;
          *(f32x4*)(Obuf + (size_t)qloc * 128 + d) = v;
        }
    }
    __syncthreads();
    if (s == 0) {
      float o[4][16];
      float ss = 0.f;
#pragma unroll
      for (int mt4 = 0; mt4 < 4; ++mt4)
#pragma unroll
        for (int q2 = 0; q2 < 4; ++q2) {
          const int d = mt4 * 32 + q2 * 8 + hi * 4;
          f32x4 ov = *(const f32x4*)(Obuf + (size_t)qloc * 128 + d);
#pragma unroll
          for (int e = 0; e < 4; ++e) {
            const float v = accv[mt4][q2 * 4 + e] * rl - lam * ov[e];
            o[mt4][q2 * 4 + e] = v;
            ss += v * v;
          }
        }
      ss += __shfl_xor(ss, 32);
      const float sc = rsqrtf(ss * (1.0f / 128.f) + 1e-5f) * ONE_MINUS_LAMBDA_INIT;
      const size_t grow = bt0 + q0 + qloc;
#pragma unroll
      for (int mt4 = 0; mt4 < 4; ++mt4)
#pragma unroll
        for (int q2 = 0; q2 < 4; ++q2) {
          const int d = mt4 * 32 + q2 * 8 + hi * 4;
          bf16x4 v;
#pragma unroll
          for (int e = 0; e < 4; ++e) v[e] = (bf16_t)(o[mt4][q2 * 4 + e] * sc);
          *(bf16x4*)(attnb + grow * 2048 + h * 128 + d) = v;
        }
    }
    __syncthreads();  // Obuf reads done before next half re-stages K
  }
}

// ---------------------------------------------------------------- launch
extern "C" void kernel_launch(void* const* d_in, const int* in_sizes, int n_in,
                              void* d_out, int out_size, void* d_ws, size_t ws_size,
                              hipStream_t stream) {
  const float* x   = (const float*)d_in[0];
  const float* Wq  = (const float*)d_in[1];
  const float* Wk  = (const float*)d_in[2];
  const float* Wv  = (const float*)d_in[3];
  const float* Wo  = (const float*)d_in[4];
  const float* lq1 = (const float*)d_in[5];
  const float* lk1 = (const float*)d_in[6];
  const float* lq2 = (const float*)d_in[7];
  const float* lk2 = (const float*)d_in[8];

  char* ws = (char*)d_ws;
  bf16_t* xb    = (bf16_t*)(ws + 0);                 // 16 MB [4096,2048]
  bf16_t* wqT   = (bf16_t*)(ws + 16777216);          // 8 MB (wkT contiguous after)
  bf16_t* wvT   = (bf16_t*)(ws + 33554432);          // 8 MB
  bf16_t* woT   = (bf16_t*)(ws + 41943040);          // 8 MB
  bf16_t* Qb    = (bf16_t*)(ws + 50331648);          // 16 MB (Kb contiguous)
  bf16_t* Kb    = (bf16_t*)(ws + 67108864);          // 16 MB
  bf16_t* Vfb   = (bf16_t*)(ws + 16777216);          // 16 MB frag-ordered V
                                                     //   (aliases wqT|wkT; written
                                                     //    only after QK GEMM done)
  bf16_t* attnb = (bf16_t*)(ws + 0);                 // aliases xb (dead then)
  float*  lamP  = (float*)(ws + 83886080);

  hipFuncSetAttribute((const void*)gemm256,
                      hipFuncAttributeMaxDynamicSharedMemorySize, 131072);

  PrepArgs pa;
  pa.x = x; pa.xb = xb;
  pa.W[0] = Wq; pa.W[1] = Wk; pa.W[2] = Wv; pa.W[3] = Wo;
  pa.WT[0] = wqT; pa.WT[1] = wqT + 4194304; pa.WT[2] = wvT; pa.WT[3] = woT;
  pa.sc[0] = 0.125f * L2E; pa.sc[1] = 1.0f; pa.sc[2] = 1.0f; pa.sc[3] = 1.0f;
  pa.lq1 = lq1; pa.lk1 = lk1; pa.lq2 = lq2; pa.lk2 = lk2; pa.lam = lamP;
  prep<<<8193, 256, 0, stream>>>(pa);

  // QK merged GEMM: N=4096 over contiguous wqT|wkT; 256 blocks = exact CU fill
  gemm256<<<dim3(16, 16), 512, 131072, stream>>>(xb, wqT, Qb);
  // V GEMM (frag-ordered out); Vfb aliases wqT|wkT, safe after gemm256
  gemm_bt<1><<<dim3(32, 16), 256, 0, stream>>>(xb, wvT, (void*)Vfb);

  flash_diff<<<512, 256, 0, stream>>>(Qb, Kb, Vfb, attnb, lamP);

  // O projection (f32 out, 128^2 tiles)
  gemm_bt<2><<<dim3(32, 16), 256, 0, stream>>>(attnb, woT, d_out);
}